// Round 8
// baseline (34.939 us; speedup 1.0000x reference)
//
#include <hip/hip_runtime.h>
#include <math.h>

#define BB 4
#define NN 512
#define F_IN 256
#define F_OUT 128
#define HH 64
#define NEG_INF_F -1e30f
#define LALPHA 0.01f

typedef float f32x2 __attribute__((ext_vector_type(2)));

// ============================================================================
// K1: h = x@W^T + bW ; hi = h@A1a^T + b1 ; hjP[b][k/4][n][k&3] = h@A1b^T packed
// 8 rows per block, 256 blocks x 512 threads, K-split(4) + LDS reduce
// ============================================================================
__global__ __launch_bounds__(512) void k_proj(
    const float* __restrict__ x, const float* __restrict__ W,
    const float* __restrict__ bW, const float* __restrict__ A1,
    const float* __restrict__ b1,
    float* __restrict__ h, float* __restrict__ hi, float* __restrict__ hjP)
{
    const int row0 = blockIdx.x * 8;     // global row (b*N + n)
    const int b    = row0 >> 9;
    const int nl0  = row0 & 511;
    const int tid  = threadIdx.x;

    __shared__ float xs[8 * F_IN];           // 8 KB
    __shared__ float hs[8 * F_OUT];          // 4 KB
    __shared__ float hjs[8 * HH];            // 2 KB
    __shared__ float red[4][8][F_OUT];       // 16 KB

    #pragma unroll
    for (int t = 0; t < 4; ++t)
        xs[tid + t * 512] = x[(size_t)row0 * F_IN + tid + t * 512];
    __syncthreads();

    // ---- h: thread = (o = tid&127, K-quarter = tid>>7), 8 rows each ----
    {
        const int o  = tid & 127;
        const int kq = tid >> 7;             // 0..3, 64-float K chunk
        float acc[8] = {0, 0, 0, 0, 0, 0, 0, 0};
        const float4* wr = (const float4*)(W + (size_t)o * F_IN + kq * 64);
        #pragma unroll 4
        for (int it = 0; it < 16; ++it) {
            const float4 wv = wr[it];
            #pragma unroll
            for (int r = 0; r < 8; ++r) {
                const float4 xv = *((const float4*)(xs + r * F_IN + kq * 64) + it);
                acc[r] = fmaf(xv.x, wv.x, acc[r]);
                acc[r] = fmaf(xv.y, wv.y, acc[r]);
                acc[r] = fmaf(xv.z, wv.z, acc[r]);
                acc[r] = fmaf(xv.w, wv.w, acc[r]);
            }
        }
        #pragma unroll
        for (int r = 0; r < 8; ++r) red[kq][r][o] = acc[r];
    }
    __syncthreads();
    #pragma unroll
    for (int t = 0; t < 2; ++t) {
        const int idx = tid + t * 512;      // 1024 = 8 rows x 128 o
        const int r = idx >> 7, o = idx & 127;
        const float v = red[0][r][o] + red[1][r][o] + red[2][r][o] + red[3][r][o] + bW[o];
        h[((size_t)row0 + r) * F_OUT + o] = v;
        hs[r * F_OUT + o] = v;
    }
    __syncthreads();

    // ---- hi+b1 / hj : thread = (kh2 = tid&127 -> (k,half), O-quarter = tid>>7) ----
    {
        const int kh2  = tid & 127;
        const int k    = kh2 & 63, half = kh2 >> 6;
        const int oq   = tid >> 7;           // 0..3, 32-float O chunk
        float acc[8] = {0, 0, 0, 0, 0, 0, 0, 0};
        const float4* ar = (const float4*)(A1 + (size_t)k * (2 * F_OUT) + half * F_OUT + oq * 32);
        #pragma unroll
        for (int it = 0; it < 8; ++it) {
            const float4 av = ar[it];
            #pragma unroll
            for (int r = 0; r < 8; ++r) {
                const float4 hv = *((const float4*)(hs + r * F_OUT + oq * 32) + it);
                acc[r] = fmaf(hv.x, av.x, acc[r]);
                acc[r] = fmaf(hv.y, av.y, acc[r]);
                acc[r] = fmaf(hv.z, av.z, acc[r]);
                acc[r] = fmaf(hv.w, av.w, acc[r]);
            }
        }
        __syncthreads();                    // red free (h combine done)
        #pragma unroll
        for (int r = 0; r < 8; ++r) red[oq][r][kh2] = acc[r];
    }
    __syncthreads();
    #pragma unroll
    for (int t = 0; t < 2; ++t) {
        const int idx = tid + t * 512;      // 1024 = 8 rows x 128 kh2
        const int r = idx >> 7, kh2 = idx & 127;
        const float v = red[0][r][kh2] + red[1][r][kh2] + red[2][r][kh2] + red[3][r][kh2];
        if (kh2 < 64) hi[((size_t)row0 + r) * HH + kh2] = v + b1[kh2];
        else          hjs[r * HH + (kh2 - 64)] = v;
    }
    __syncthreads();
    // ---- packed store: hjP[((b*16 + k4)*512 + n)*4 + c] = hj[n][k4*4+c] ----
    if (tid < 128) {
        const int k4 = tid >> 3, rr = tid & 7;
        float4 v;
        v.x = hjs[rr * HH + k4 * 4 + 0];
        v.y = hjs[rr * HH + k4 * 4 + 1];
        v.z = hjs[rr * HH + k4 * 4 + 2];
        v.w = hjs[rr * HH + k4 * 4 + 3];
        *(float4*)(hjP + (((size_t)b * 16 + k4) * NN + nl0 + rr) * 4) = v;
    }
}

// ============================================================================
// K2: fused scores + exp + aggregation (unscaled) + per-block softmax stats.
// Block = 8 i-rows x ALL 512 j. 256 blocks x 512 threads, thread = one j.
// Packed-f32 inner loops; hj in VGPRs (loaded once); hi via s_load.
// ============================================================================
__global__ __launch_bounds__(512) void k_score_agg(
    const float* __restrict__ hi, const float* __restrict__ hjP,
    const float* __restrict__ A2, const float* __restrict__ b2,
    const float* __restrict__ adj, const float* __restrict__ h,
    float* __restrict__ y, float* __restrict__ stat_m, float* __restrict__ stat_s)
{
    const int blk   = blockIdx.x;        // b*64 + itile
    const int b     = blk >> 6;
    const int itile = blk & 63;
    const int i0    = itile * 8;
    const int tid   = threadIdx.x;
    const int j     = tid;               // this thread's column

    __shared__ float a2s[HH];
    __shared__ float e_lds[NN][12];         // 24 KB  (exp'd weights, padded)
    __shared__ float red[4][8][F_OUT];      // 16 KB
    __shared__ float rtmp[16];

    if (tid < HH) a2s[tid] = A2[tid];
    __syncthreads();

    // ---- hoist hj(j) into registers: 16 independent b128 loads ----
    float4 hjr[16];
    const float4* hjp = (const float4*)hjP + (size_t)b * 16 * NN + j;
    #pragma unroll
    for (int k4 = 0; k4 < 16; ++k4) hjr[k4] = hjp[(size_t)k4 * NN];

    // ---- wave-uniform hi row base -> scalar loads ----
    const int rowu = __builtin_amdgcn_readfirstlane(b * NN + i0);
    const float* hrow = hi + (size_t)rowu * HH;

    // ---- scores for 8 rows x column j (packed f32) ----
    const f32x2 z2 = {0.0f, 0.0f};
    f32x2 s2[8] = {z2, z2, z2, z2, z2, z2, z2, z2};
    #pragma unroll
    for (int k4 = 0; k4 < 16; ++k4) {
        const f32x2 a2lo = *(const f32x2*)(a2s + k4 * 4);
        const f32x2 a2hi = *(const f32x2*)(a2s + k4 * 4 + 2);
        const f32x2 hjlo = {hjr[k4].x, hjr[k4].y};
        const f32x2 hjhi = {hjr[k4].z, hjr[k4].w};
        #pragma unroll
        for (int r = 0; r < 8; ++r) {
            const float* hp = hrow + r * HH + k4 * 4;   // uniform -> s_load
            const f32x2 hlo = {hp[0], hp[1]};
            const f32x2 hhi = {hp[2], hp[3]};
            s2[r] = __builtin_elementwise_fma(
                        __builtin_elementwise_max(hlo + hjlo, z2), a2lo, s2[r]);
            s2[r] = __builtin_elementwise_fma(
                        __builtin_elementwise_max(hhi + hjhi, z2), a2hi, s2[r]);
        }
    }
    float s8[8];
    #pragma unroll
    for (int r = 0; r < 8; ++r) s8[r] = s2[r].x + s2[r].y;

    const float b2v = b2[0];
    float lmax = -INFINITY;
    #pragma unroll
    for (int r = 0; r < 8; ++r) {
        float v = s8[r] + b2v;
        v = (v >= 0.0f) ? v : LALPHA * v;
        const float a = adj[((size_t)b * NN + i0 + r) * NN + j];
        v = (a != 0.0f) ? v : NEG_INF_F;
        s8[r] = v;
        lmax = fmaxf(lmax, v);
    }

    // ---- block max ----
    #pragma unroll
    for (int off = 32; off; off >>= 1) lmax = fmaxf(lmax, __shfl_xor(lmax, off, 64));
    if ((tid & 63) == 0) rtmp[tid >> 6] = lmax;
    __syncthreads();
    float m_blk = rtmp[0];
    #pragma unroll
    for (int w = 1; w < 8; ++w) m_blk = fmaxf(m_blk, rtmp[w]);

    // ---- exp -> LDS, block sum ----
    float4 wlo, whi;
    wlo.x = __expf(s8[0] - m_blk);
    wlo.y = __expf(s8[1] - m_blk);
    wlo.z = __expf(s8[2] - m_blk);
    wlo.w = __expf(s8[3] - m_blk);
    whi.x = __expf(s8[4] - m_blk);
    whi.y = __expf(s8[5] - m_blk);
    whi.z = __expf(s8[6] - m_blk);
    whi.w = __expf(s8[7] - m_blk);
    *(float4*)(&e_lds[j][0]) = wlo;
    *(float4*)(&e_lds[j][4]) = whi;
    float ls = wlo.x + wlo.y + wlo.z + wlo.w + whi.x + whi.y + whi.z + whi.w;
    #pragma unroll
    for (int off = 32; off; off >>= 1) ls += __shfl_xor(ls, off, 64);
    if ((tid & 63) == 0) rtmp[8 + (tid >> 6)] = ls;
    __syncthreads();
    if (tid == 0) {
        stat_m[blk] = m_blk;
        float ssum = 0.0f;
        #pragma unroll
        for (int w = 0; w < 8; ++w) ssum += rtmp[8 + w];
        stat_s[blk] = ssum;
    }

    // ---- aggregate: y += w * h over all 512 j (packed f32, 4-way j split) ----
    {
        const int o = tid & 127;
        const int p = tid >> 7;
        f32x2 acc2[4] = {z2, z2, z2, z2};
        const float* hb = h + (size_t)b * NN * F_OUT;
        #pragma unroll 4
        for (int q = 0; q < 128; ++q) {
            const int jl = p * 128 + q;
            const float hv = hb[(size_t)jl * F_OUT + o];
            const f32x2 hv2 = {hv, hv};
            const f32x2 wa = *(const f32x2*)&e_lds[jl][0];
            const f32x2 wb = *(const f32x2*)&e_lds[jl][2];
            const f32x2 wc = *(const f32x2*)&e_lds[jl][4];
            const f32x2 wd = *(const f32x2*)&e_lds[jl][6];
            acc2[0] = __builtin_elementwise_fma(wa, hv2, acc2[0]);
            acc2[1] = __builtin_elementwise_fma(wb, hv2, acc2[1]);
            acc2[2] = __builtin_elementwise_fma(wc, hv2, acc2[2]);
            acc2[3] = __builtin_elementwise_fma(wd, hv2, acc2[3]);
        }
        #pragma unroll
        for (int c = 0; c < 4; ++c) {
            red[p][2 * c + 0][o] = acc2[c].x;
            red[p][2 * c + 1][o] = acc2[c].y;
        }
    }
    __syncthreads();
    #pragma unroll
    for (int t = 0; t < 2; ++t) {
        const int idx = tid + t * 512;   // 1024 = 8 rows x 128 o
        const int r = idx >> 7, oo = idx & 127;
        y[(size_t)blk * 1024 + idx] =
            red[0][r][oo] + red[1][r][oo] + red[2][r][oo] + red[3][r][oo];
    }
}

// ============================================================================
// K3: global M,S per batch (single-wave shfl reduce over 64 stats) + elu
// 256 blocks x 256 threads, 1024 outputs each (float4 path)
// ============================================================================
__global__ __launch_bounds__(256) void k_finish(
    const float* __restrict__ y, const float* __restrict__ stat_m,
    const float* __restrict__ stat_s, float* __restrict__ out)
{
    const int blk   = blockIdx.x;       // b*64 + itile
    const int b     = blk >> 6;
    const int itile = blk & 63;
    const int tid   = threadIdx.x;

    // each wave redundantly reduces the 64 per-tile stats (lane = tile)
    const int lane = tid & 63;
    const float m = stat_m[b * 64 + lane];
    float lm = m;
    #pragma unroll
    for (int off = 32; off; off >>= 1) lm = fmaxf(lm, __shfl_xor(lm, off, 64));
    const float M = lm;
    float sv = stat_s[b * 64 + lane] * __expf(m - M);
    #pragma unroll
    for (int off = 32; off; off >>= 1) sv += __shfl_xor(sv, off, 64);
    const float sc = __expf(stat_m[b * 64 + itile] - M) / sv;

    const float4* y4 = (const float4*)(y + (size_t)blk * 1024);
    float4* ob4 = (float4*)(out + ((size_t)b * NN + itile * 8) * F_OUT);

    const float4 v0 = y4[tid];
    float4 vv;
    vv.x = v0.x * sc;
    vv.y = v0.y * sc;
    vv.z = v0.z * sc;
    vv.w = v0.w * sc;
    vv.x = (vv.x > 0.0f) ? vv.x : expm1f(vv.x);
    vv.y = (vv.y > 0.0f) ? vv.y : expm1f(vv.y);
    vv.z = (vv.z > 0.0f) ? vv.z : expm1f(vv.z);
    vv.w = (vv.w > 0.0f) ? vv.w : expm1f(vv.w);
    ob4[tid] = vv;
}

extern "C" void kernel_launch(void* const* d_in, const int* in_sizes, int n_in,
                              void* d_out, int out_size, void* d_ws, size_t ws_size,
                              hipStream_t stream) {
    const float* x   = (const float*)d_in[0];
    const float* adj = (const float*)d_in[1];
    const float* W   = (const float*)d_in[2];
    const float* bW  = (const float*)d_in[3];
    const float* A1  = (const float*)d_in[4];
    const float* b1  = (const float*)d_in[5];
    const float* A2  = (const float*)d_in[6];
    const float* b2  = (const float*)d_in[7];
    float* out = (float*)d_out;

    float* ws = (float*)d_ws;
    float* h      = ws;                                   // B*N*F_OUT = 262144
    float* hi     = h   + (size_t)BB * NN * F_OUT;        // B*N*H     = 131072
    float* hjP    = hi  + (size_t)BB * NN * HH;           // B*H*N     = 131072 (packed)
    float* y      = hjP + (size_t)BB * HH * NN;           // 256*1024  = 262144
    float* stat_m = y   + (size_t)256 * 1024;             // 256
    float* stat_s = stat_m + 256;                         // 256

    k_proj     <<<BB * 64, 512, 0, stream>>>(x, W, bW, A1, b1, h, hi, hjP);
    k_score_agg<<<BB * 64, 512, 0, stream>>>(hi, hjP, A2, b2, adj, h, y, stat_m, stat_s);
    k_finish   <<<BB * 64, 256, 0, stream>>>(y, stat_m, stat_s, out);
}

// Round 9
// 32.829 us; speedup vs baseline: 1.0643x; 1.0643x over previous
//
#include <hip/hip_runtime.h>
#include <math.h>

#define BB 4
#define NN 512
#define F_IN 256
#define F_OUT 128
#define HH 64
#define NEG_INF_F -1e30f
#define LALPHA 0.01f

typedef float f32x2 __attribute__((ext_vector_type(2)));

// ============================================================================
// K1: h = x@W^T + bW ; hi = h@A1a^T + b1 ; hjP[b][k/4][n][k&3] = h@A1b^T packed
// 8 rows per block, 256 blocks x 512 threads, K-split(4) + LDS reduce
// ============================================================================
__global__ __launch_bounds__(512) void k_proj(
    const float* __restrict__ x, const float* __restrict__ W,
    const float* __restrict__ bW, const float* __restrict__ A1,
    const float* __restrict__ b1,
    float* __restrict__ h, float* __restrict__ hi, float* __restrict__ hjP)
{
    const int row0 = blockIdx.x * 8;     // global row (b*N + n)
    const int b    = row0 >> 9;
    const int nl0  = row0 & 511;
    const int tid  = threadIdx.x;

    __shared__ float xs[8 * F_IN];           // 8 KB
    __shared__ float hs[8 * F_OUT];          // 4 KB
    __shared__ float hjs[8 * HH];            // 2 KB
    __shared__ float red[4][8][F_OUT];       // 16 KB

    #pragma unroll
    for (int t = 0; t < 4; ++t)
        xs[tid + t * 512] = x[(size_t)row0 * F_IN + tid + t * 512];
    __syncthreads();

    // ---- h: thread = (o = tid&127, K-quarter = tid>>7), 8 rows each ----
    {
        const int o  = tid & 127;
        const int kq = tid >> 7;             // 0..3, 64-float K chunk
        float acc[8] = {0, 0, 0, 0, 0, 0, 0, 0};
        const float4* wr = (const float4*)(W + (size_t)o * F_IN + kq * 64);
        #pragma unroll 4
        for (int it = 0; it < 16; ++it) {
            const float4 wv = wr[it];
            #pragma unroll
            for (int r = 0; r < 8; ++r) {
                const float4 xv = *((const float4*)(xs + r * F_IN + kq * 64) + it);
                acc[r] = fmaf(xv.x, wv.x, acc[r]);
                acc[r] = fmaf(xv.y, wv.y, acc[r]);
                acc[r] = fmaf(xv.z, wv.z, acc[r]);
                acc[r] = fmaf(xv.w, wv.w, acc[r]);
            }
        }
        #pragma unroll
        for (int r = 0; r < 8; ++r) red[kq][r][o] = acc[r];
    }
    __syncthreads();
    #pragma unroll
    for (int t = 0; t < 2; ++t) {
        const int idx = tid + t * 512;      // 1024 = 8 rows x 128 o
        const int r = idx >> 7, o = idx & 127;
        const float v = red[0][r][o] + red[1][r][o] + red[2][r][o] + red[3][r][o] + bW[o];
        h[((size_t)row0 + r) * F_OUT + o] = v;
        hs[r * F_OUT + o] = v;
    }
    __syncthreads();

    // ---- hi+b1 / hj : thread = (kh2 = tid&127 -> (k,half), O-quarter = tid>>7) ----
    {
        const int kh2  = tid & 127;
        const int k    = kh2 & 63, half = kh2 >> 6;
        const int oq   = tid >> 7;           // 0..3, 32-float O chunk
        float acc[8] = {0, 0, 0, 0, 0, 0, 0, 0};
        const float4* ar = (const float4*)(A1 + (size_t)k * (2 * F_OUT) + half * F_OUT + oq * 32);
        #pragma unroll
        for (int it = 0; it < 8; ++it) {
            const float4 av = ar[it];
            #pragma unroll
            for (int r = 0; r < 8; ++r) {
                const float4 hv = *((const float4*)(hs + r * F_OUT + oq * 32) + it);
                acc[r] = fmaf(hv.x, av.x, acc[r]);
                acc[r] = fmaf(hv.y, av.y, acc[r]);
                acc[r] = fmaf(hv.z, av.z, acc[r]);
                acc[r] = fmaf(hv.w, av.w, acc[r]);
            }
        }
        __syncthreads();                    // red free (h combine done)
        #pragma unroll
        for (int r = 0; r < 8; ++r) red[oq][r][kh2] = acc[r];
    }
    __syncthreads();
    #pragma unroll
    for (int t = 0; t < 2; ++t) {
        const int idx = tid + t * 512;      // 1024 = 8 rows x 128 kh2
        const int r = idx >> 7, kh2 = idx & 127;
        const float v = red[0][r][kh2] + red[1][r][kh2] + red[2][r][kh2] + red[3][r][kh2];
        if (kh2 < 64) hi[((size_t)row0 + r) * HH + kh2] = v + b1[kh2];
        else          hjs[r * HH + (kh2 - 64)] = v;
    }
    __syncthreads();
    // ---- packed store: hjP[((b*16 + k4)*512 + n)*4 + c] = hj[n][k4*4+c] ----
    if (tid < 128) {
        const int k4 = tid >> 3, rr = tid & 7;
        float4 v;
        v.x = hjs[rr * HH + k4 * 4 + 0];
        v.y = hjs[rr * HH + k4 * 4 + 1];
        v.z = hjs[rr * HH + k4 * 4 + 2];
        v.w = hjs[rr * HH + k4 * 4 + 3];
        *(float4*)(hjP + (((size_t)b * 16 + k4) * NN + nl0 + rr) * 4) = v;
    }
}

// ============================================================================
// K2: fused scores + exp + aggregation (unscaled) + per-block softmax stats.
// Block = 8 i-rows x 256 j (one j-half). 512 blocks x 512 threads (2/CU).
// Packed-f32 (v_pk_fma/v_pk_max) inner loops; hj in VGPRs; hi via s_load.
// ============================================================================
__global__ __launch_bounds__(512, 2) void k_score_agg(
    const float* __restrict__ hi, const float* __restrict__ hjP,
    const float* __restrict__ A2, const float* __restrict__ b2,
    const float* __restrict__ adj, const float* __restrict__ h,
    float* __restrict__ y, float* __restrict__ stat_m, float* __restrict__ stat_s)
{
    const int blk   = blockIdx.x;        // b*128 + itile*2 + jh
    const int b     = blk >> 7;
    const int itile = (blk >> 1) & 63;
    const int jh    = blk & 1;
    const int i0    = itile * 8;
    const int tid   = threadIdx.x;
    const int jt    = tid & 255;         // local j
    const int j     = jh * 256 + jt;

    __shared__ float a2s[HH];
    __shared__ float e_lds[256][12];        // 12 KB  (exp'd weights, padded)
    __shared__ float red[4][8][F_OUT];      // 16 KB
    __shared__ float rtmp[16];

    if (tid < HH) a2s[tid] = A2[tid];
    __syncthreads();

    // ---- hoist hj(j) into registers: 16 independent b128 loads ----
    float4 hjr[16];
    const float4* hjp = (const float4*)hjP + (size_t)b * 16 * NN + j;
    #pragma unroll
    for (int k4 = 0; k4 < 16; ++k4) hjr[k4] = hjp[(size_t)k4 * NN];

    // ---- wave-uniform hi row base -> scalar loads ----
    const int rowu = __builtin_amdgcn_readfirstlane(b * NN + i0 + (tid >> 8) * 4);
    const float* hrow = hi + (size_t)rowu * HH;

    // ---- scores for 4 rows x column j (packed f32) ----
    const f32x2 z2 = {0.0f, 0.0f};
    f32x2 s2[4] = {z2, z2, z2, z2};
    #pragma unroll
    for (int k4 = 0; k4 < 16; ++k4) {
        const f32x2 a2lo = *(const f32x2*)(a2s + k4 * 4);
        const f32x2 a2hi = *(const f32x2*)(a2s + k4 * 4 + 2);
        const f32x2 hjlo = {hjr[k4].x, hjr[k4].y};
        const f32x2 hjhi = {hjr[k4].z, hjr[k4].w};
        #pragma unroll
        for (int r = 0; r < 4; ++r) {
            const float* hp = hrow + r * HH + k4 * 4;   // uniform -> s_load
            const f32x2 hlo = {hp[0], hp[1]};
            const f32x2 hhi = {hp[2], hp[3]};
            s2[r] = __builtin_elementwise_fma(
                        __builtin_elementwise_max(hlo + hjlo, z2), a2lo, s2[r]);
            s2[r] = __builtin_elementwise_fma(
                        __builtin_elementwise_max(hhi + hjhi, z2), a2hi, s2[r]);
        }
    }
    float s4[4];
    #pragma unroll
    for (int r = 0; r < 4; ++r) s4[r] = s2[r].x + s2[r].y;

    const float b2v = b2[0];
    const int rh = tid >> 8;
    float lmax = -INFINITY;
    #pragma unroll
    for (int r = 0; r < 4; ++r) {
        float v = s4[r] + b2v;
        v = (v >= 0.0f) ? v : LALPHA * v;
        const float a = adj[((size_t)b * NN + i0 + rh * 4 + r) * NN + j];
        v = (a != 0.0f) ? v : NEG_INF_F;
        s4[r] = v;
        lmax = fmaxf(lmax, v);
    }

    // ---- block max ----
    #pragma unroll
    for (int off = 32; off; off >>= 1) lmax = fmaxf(lmax, __shfl_xor(lmax, off, 64));
    if ((tid & 63) == 0) rtmp[tid >> 6] = lmax;
    __syncthreads();
    float m_blk = rtmp[0];
    #pragma unroll
    for (int w = 1; w < 8; ++w) m_blk = fmaxf(m_blk, rtmp[w]);

    // ---- exp -> LDS, block sum ----
    float4 w4;
    w4.x = __expf(s4[0] - m_blk);
    w4.y = __expf(s4[1] - m_blk);
    w4.z = __expf(s4[2] - m_blk);
    w4.w = __expf(s4[3] - m_blk);
    *(float4*)(&e_lds[jt][rh * 4]) = w4;
    float ls = w4.x + w4.y + w4.z + w4.w;
    #pragma unroll
    for (int off = 32; off; off >>= 1) ls += __shfl_xor(ls, off, 64);
    if ((tid & 63) == 0) rtmp[8 + (tid >> 6)] = ls;
    __syncthreads();
    if (tid == 0) {
        stat_m[blk] = m_blk;
        float ssum = 0.0f;
        #pragma unroll
        for (int w = 0; w < 8; ++w) ssum += rtmp[8 + w];
        stat_s[blk] = ssum;
    }

    // ---- aggregate: y += w * h over this block's 256 j (packed f32) ----
    {
        const int o = tid & 127;
        const int p = tid >> 7;          // 4-way j split
        f32x2 acc2[4] = {z2, z2, z2, z2};
        const float* hb = h + (size_t)b * NN * F_OUT;
        #pragma unroll 4
        for (int q = 0; q < 64; ++q) {
            const int jl = p * 64 + q;
            const float hv = hb[(size_t)(jh * 256 + jl) * F_OUT + o];
            const f32x2 hv2 = {hv, hv};
            const f32x2 wa = *(const f32x2*)&e_lds[jl][0];
            const f32x2 wb = *(const f32x2*)&e_lds[jl][2];
            const f32x2 wc = *(const f32x2*)&e_lds[jl][4];
            const f32x2 wd = *(const f32x2*)&e_lds[jl][6];
            acc2[0] = __builtin_elementwise_fma(wa, hv2, acc2[0]);
            acc2[1] = __builtin_elementwise_fma(wb, hv2, acc2[1]);
            acc2[2] = __builtin_elementwise_fma(wc, hv2, acc2[2]);
            acc2[3] = __builtin_elementwise_fma(wd, hv2, acc2[3]);
        }
        #pragma unroll
        for (int c = 0; c < 4; ++c) {
            red[p][2 * c + 0][o] = acc2[c].x;
            red[p][2 * c + 1][o] = acc2[c].y;
        }
    }
    __syncthreads();
    #pragma unroll
    for (int t = 0; t < 2; ++t) {
        const int idx = tid + t * 512;   // 1024 = 8 rows x 128 o
        const int r = idx >> 7, oo = idx & 127;
        y[(size_t)blk * 1024 + idx] =
            red[0][r][oo] + red[1][r][oo] + red[2][r][oo] + red[3][r][oo];
    }
}

// ============================================================================
// K3: global M,S per batch (single-wave shfl reduce over 128 stats) +
//     combine the two j-half partials + elu.
// 256 blocks x 256 threads, 1024 outputs each (float4 path)
// ============================================================================
__global__ __launch_bounds__(256) void k_finish(
    const float* __restrict__ y, const float* __restrict__ stat_m,
    const float* __restrict__ stat_s, float* __restrict__ out)
{
    const int blk   = blockIdx.x;       // b*64 + itile
    const int b     = blk >> 6;
    const int itile = blk & 63;
    const int tid   = threadIdx.x;

    // each wave redundantly reduces the 128 per-half stats (lane = stat pair)
    const int lane = tid & 63;
    const float m0 = stat_m[b * 128 + 2 * lane + 0];
    const float m1 = stat_m[b * 128 + 2 * lane + 1];
    float lm = fmaxf(m0, m1);
    #pragma unroll
    for (int off = 32; off; off >>= 1) lm = fmaxf(lm, __shfl_xor(lm, off, 64));
    const float M = lm;
    float sv = stat_s[b * 128 + 2 * lane + 0] * __expf(m0 - M)
             + stat_s[b * 128 + 2 * lane + 1] * __expf(m1 - M);
    #pragma unroll
    for (int off = 32; off; off >>= 1) sv += __shfl_xor(sv, off, 64);
    const float invS = 1.0f / sv;

    const float sc0 = __expf(stat_m[b * 128 + itile * 2 + 0] - M) * invS;
    const float sc1 = __expf(stat_m[b * 128 + itile * 2 + 1] - M) * invS;
    const float4* y04 = (const float4*)(y + (size_t)(b * 128 + itile * 2 + 0) * 1024);
    const float4* y14 = (const float4*)(y + (size_t)(b * 128 + itile * 2 + 1) * 1024);
    float4* ob4 = (float4*)(out + ((size_t)b * NN + itile * 8) * F_OUT);

    const float4 v0 = y04[tid];
    const float4 v1 = y14[tid];
    float4 vv;
    vv.x = v0.x * sc0 + v1.x * sc1;
    vv.y = v0.y * sc0 + v1.y * sc1;
    vv.z = v0.z * sc0 + v1.z * sc1;
    vv.w = v0.w * sc0 + v1.w * sc1;
    vv.x = (vv.x > 0.0f) ? vv.x : expm1f(vv.x);
    vv.y = (vv.y > 0.0f) ? vv.y : expm1f(vv.y);
    vv.z = (vv.z > 0.0f) ? vv.z : expm1f(vv.z);
    vv.w = (vv.w > 0.0f) ? vv.w : expm1f(vv.w);
    ob4[tid] = vv;
}

extern "C" void kernel_launch(void* const* d_in, const int* in_sizes, int n_in,
                              void* d_out, int out_size, void* d_ws, size_t ws_size,
                              hipStream_t stream) {
    const float* x   = (const float*)d_in[0];
    const float* adj = (const float*)d_in[1];
    const float* W   = (const float*)d_in[2];
    const float* bW  = (const float*)d_in[3];
    const float* A1  = (const float*)d_in[4];
    const float* b1  = (const float*)d_in[5];
    const float* A2  = (const float*)d_in[6];
    const float* b2  = (const float*)d_in[7];
    float* out = (float*)d_out;

    float* ws = (float*)d_ws;
    float* h      = ws;                                   // B*N*F_OUT = 262144
    float* hi     = h   + (size_t)BB * NN * F_OUT;        // B*N*H     = 131072
    float* hjP    = hi  + (size_t)BB * NN * HH;           // B*H*N     = 131072 (packed)
    float* y      = hjP + (size_t)BB * HH * NN;           // 512*1024  = 524288
    float* stat_m = y   + (size_t)512 * 1024;             // 512
    float* stat_s = stat_m + 512;                         // 512

    k_proj     <<<BB * 64,  512, 0, stream>>>(x, W, bW, A1, b1, h, hi, hjP);
    k_score_agg<<<BB * 128, 512, 0, stream>>>(hi, hjP, A2, b2, adj, h, y, stat_m, stat_s);
    k_finish   <<<BB * 64,  256, 0, stream>>>(y, stat_m, stat_s, out);
}